// Round 1
// baseline (353.426 us; speedup 1.0000x reference)
//
#include <hip/hip_runtime.h>
#include <math.h>

namespace {
constexpr int kB = 8;
constexpr int kC = 256;
constexpr int kH = 128;
constexpr int kW = 128;
constexpr int kHW = kH * kW;     // 16384
constexpr int kTopK = 10;
constexpr float kThreshold = 0.5f;
constexpr float kMargin = 0.5f;
constexpr float kEps = 1e-8f;
constexpr int kMaps = 2 * kB;    // 8 loc maps then 8 det maps
}

// ---------------------------------------------------------------------------
// Kernel 1: intensity[m][p] = sqrt(sum_c fmap[c][p]^2) for all 16 maps.
// 2 pixels/thread via float2; 131072 threads = 512 blocks x 256 (8 waves/CU).
// Streams the full 256 MiB of input exactly once -> HBM-bound (~43us floor).
// ---------------------------------------------------------------------------
__global__ __launch_bounds__(256) void intensity_kernel(
    const float* __restrict__ loc, const float* __restrict__ det,
    float* __restrict__ inten) {
  const int g = blockIdx.x * blockDim.x + threadIdx.x;  // pixel-pair id
  const int groups_per_map = kHW / 2;                   // 8192
  const int m = g / groups_per_map;                     // 0..15
  const int p2 = (g - m * groups_per_map) * 2;          // pixel base
  const float* __restrict__ src = (m < kB) ? loc : det;
  const int b = m & (kB - 1);
  const float* base = src + (size_t)b * kC * kHW + p2;
  float ax = 0.f, ay = 0.f;
#pragma unroll 8
  for (int c = 0; c < kC; ++c) {
    const float2 v = *(const float2*)(base + (size_t)c * kHW);
    ax = fmaf(v.x, v.x, ax);
    ay = fmaf(v.y, v.y, ay);
  }
  float2 r;
  r.x = sqrtf(ax);
  r.y = sqrtf(ay);
  *(float2*)(inten + (size_t)m * kHW + p2) = r;
}

// ---------------------------------------------------------------------------
// Kernel 2: per map, find pixels equal to their 3x3 in-bounds max and > 0.5,
// then select top-10 by value (tie -> lowest index, matching lax.top_k).
// One block of 1024 threads per map; masked values live in 16 regs/thread
// (full 16384-pixel map) so LDS stays at ~136 B (no 64 KB static limit risk).
// Neighbor reads come from the global intensity map (64 KB -> L1/L2 hits).
// ---------------------------------------------------------------------------
__global__ __launch_bounds__(1024) void topk_kernel(
    const float* __restrict__ inten, float* __restrict__ tvals,
    int* __restrict__ tidx) {
  const int m = blockIdx.x;
  const int t = threadIdx.x;  // 0..1023
  const float* __restrict__ I = inten + (size_t)m * kHW;

  // Phase 1: masked peak values, pixel p = k*1024 + t.
  float v[16];
#pragma unroll
  for (int k = 0; k < 16; ++k) {
    const int p = k * 1024 + t;
    const int y = p >> 7;
    const int x = p & (kW - 1);
    const float c0 = I[p];
    float nmax = -INFINITY;
    for (int dy = -1; dy <= 1; ++dy) {
      const int yy = y + dy;
      if (yy < 0 || yy >= kH) continue;
      for (int dx = -1; dx <= 1; ++dx) {
        const int xx = x + dx;
        if (xx < 0 || xx >= kW) continue;
        const float n = I[yy * kW + xx];
        nmax = fmaxf(nmax, n);
      }
    }
    const bool peak = (c0 > kThreshold) && (c0 >= nmax);
    v[k] = peak ? c0 : -INFINITY;
  }

  // Phase 2: 10 rounds of block-wide argmax with removal.
  __shared__ float s_wv[16];
  __shared__ int s_wi[16];
  __shared__ float s_bv;
  __shared__ int s_bi;
  const int wave = t >> 6;
  const int lane = t & 63;

  for (int r = 0; r < kTopK; ++r) {
    float bv = v[0];
    int bi = t;  // index of k=0 element is t
#pragma unroll
    for (int k = 1; k < 16; ++k) {
      const int idx = k * 1024 + t;
      if (v[k] > bv || (v[k] == bv && idx < bi)) { bv = v[k]; bi = idx; }
    }
    // wave (64-lane) reduce, keeping lowest index on ties
    for (int off = 32; off > 0; off >>= 1) {
      const float ov = __shfl_down(bv, off, 64);
      const int oi = __shfl_down(bi, off, 64);
      if (ov > bv || (ov == bv && oi < bi)) { bv = ov; bi = oi; }
    }
    if (lane == 0) { s_wv[wave] = bv; s_wi[wave] = bi; }
    __syncthreads();
    if (t == 0) {
      float xv = s_wv[0];
      int xi = s_wi[0];
      for (int w2 = 1; w2 < 16; ++w2) {
        if (s_wv[w2] > xv || (s_wv[w2] == xv && s_wi[w2] < xi)) {
          xv = s_wv[w2];
          xi = s_wi[w2];
        }
      }
      s_bv = xv;
      s_bi = xi;
      tvals[m * kTopK + r] = xv;
      tidx[m * kTopK + r] = xi;
    }
    __syncthreads();
    const int wi = s_bi;
    if ((wi & 1023) == t) v[wi >> 10] = -INFINITY;  // remove winner
    __syncthreads();
  }
}

// ---------------------------------------------------------------------------
// Kernel 3: per sample, gather [10,256] det & loc peak features, compute
// 10x10 cosine sims (norm == top-k intensity value!), masked hinge mean.
// 8 blocks x 256 threads (thread = channel). LDS rows padded to 257 floats.
// ---------------------------------------------------------------------------
__global__ __launch_bounds__(256) void loss_kernel(
    const float* __restrict__ loc, const float* __restrict__ det,
    const float* __restrict__ tvals, const int* __restrict__ tidx,
    float* __restrict__ losses) {
  const int b = blockIdx.x;
  const int t = threadIdx.x;  // channel
  __shared__ float ds[kTopK][kC + 1];
  __shared__ float ls[kTopK][kC + 1];
  __shared__ float s_red[kC];

  float lv[kTopK], dv[kTopK];
  int li[kTopK], di[kTopK];
#pragma unroll
  for (int i = 0; i < kTopK; ++i) {
    lv[i] = tvals[b * kTopK + i];
    li[i] = tidx[b * kTopK + i];
    dv[i] = tvals[(kB + b) * kTopK + i];
    di[i] = tidx[(kB + b) * kTopK + i];
  }
  const float* lb = loc + (size_t)b * kC * kHW + (size_t)t * kHW;
  const float* db = det + (size_t)b * kC * kHW + (size_t)t * kHW;
#pragma unroll
  for (int i = 0; i < kTopK; ++i) {
    ls[i][t] = lb[li[i]];
    ds[i][t] = db[di[i]];
  }
  __syncthreads();

  float contrib = 0.f;
  if (t < kTopK * kTopK) {
    const int i = t / kTopK;  // det peak
    const int j = t % kTopK;  // loc peak
    const bool valid = (dv[i] > -1e30f) && (lv[j] > -1e30f);
    if (valid) {
      float dot = 0.f;
#pragma unroll 8
      for (int c = 0; c < kC; ++c) dot = fmaf(ds[i][c], ls[j][c], dot);
      const float na = fmaxf(dv[i], kEps);  // norm of det feat == intensity
      const float nb = fmaxf(lv[j], kEps);
      const float sim = dot / (na * nb);
      contrib = fmaxf(sim - kMargin, 0.f);
    }
  }
  s_red[t] = contrib;
  __syncthreads();
  if (t == 0) {
    int nd = 0, nl = 0;
    for (int i = 0; i < kTopK; ++i) {
      nd += (dv[i] > -1e30f) ? 1 : 0;
      nl += (lv[i] > -1e30f) ? 1 : 0;
    }
    float s = 0.f;
    for (int k = 0; k < kTopK * kTopK; ++k) s += s_red[k];
    const int np = nd * nl;
    losses[b] = (np > 0) ? (s / (float)np) : 0.f;
  }
}

// ---------------------------------------------------------------------------
// Kernel 4: mean over batch.
// ---------------------------------------------------------------------------
__global__ void final_kernel(const float* __restrict__ losses,
                             float* __restrict__ out) {
  if (threadIdx.x == 0 && blockIdx.x == 0) {
    float s = 0.f;
    for (int i = 0; i < kB; ++i) s += losses[i];
    out[0] = s / (float)kB;
  }
}

extern "C" void kernel_launch(void* const* d_in, const int* in_sizes, int n_in,
                              void* d_out, int out_size, void* d_ws,
                              size_t ws_size, hipStream_t stream) {
  const float* loc = (const float*)d_in[0];
  const float* det = (const float*)d_in[1];
  float* out = (float*)d_out;

  // Workspace layout (floats): intensity [16*16384] | tvals [160] |
  // tidx [160 ints] | losses [8]  -> ~1.05 MB total.
  float* wsf = (float*)d_ws;
  float* inten = wsf;
  float* tvals = wsf + (size_t)kMaps * kHW;
  int* tidx = (int*)(tvals + kMaps * kTopK);
  float* losses = (float*)(tidx + kMaps * kTopK);

  const int k1_threads = kMaps * kHW / 2;  // 131072
  intensity_kernel<<<dim3(k1_threads / 256), dim3(256), 0, stream>>>(loc, det,
                                                                     inten);
  topk_kernel<<<dim3(kMaps), dim3(1024), 0, stream>>>(inten, tvals, tidx);
  loss_kernel<<<dim3(kB), dim3(kC), 0, stream>>>(loc, det, tvals, tidx,
                                                 losses);
  final_kernel<<<dim3(1), dim3(64), 0, stream>>>(losses, out);
}